// Round 1
// baseline (340.628 us; speedup 1.0000x reference)
//
#include <hip/hip_runtime.h>
#include <float.h>
#include <math.h>

// NNConv net: 2x edge-conditioned conv (scalar edge attr) + 2 FC + log_softmax.
// Key insight: edge MLP input is a SCALAR a_e, so the generated per-edge weight
// matrix W_e = sum_k relu(a_e*wa_k+ba_k)*wb_k + bb is piecewise-linear in a_e:
// W_e = a_e*U_s + V_s per breakpoint segment s (<=26 segments). Precompute U/V,
// then per-edge cost is 2*IC*OC MACs instead of 25*IC*OC.

#define NCONST 25

__device__ __forceinline__ void atomicMaxFloat(float* addr, float val) {
    // Works for mixed-sign floats with monotone bit patterns.
    if (val >= 0.f) atomicMax((int*)addr, __float_as_int(val));
    else            atomicMin((unsigned int*)addr, __float_as_uint(val));
}

__global__ void fill_neg_kernel(float* p, int n) {
    int i = blockIdx.x * blockDim.x + threadIdx.x;
    int stride = gridDim.x * blockDim.x;
    for (; i < n; i += stride) p[i] = -FLT_MAX;
}

// Single thread: breakpoints t_k = -ba_k/wa_k, insertion sort, and for each of
// the m+1 segments a 25-bit mask of which relu units are active there.
__global__ void prep_kernel(const float* w1a, const float* b1a,
                            const float* w2a, const float* b2a,
                            int* meta, float* t1, float* t2,
                            unsigned* mask1, unsigned* mask2) {
    if (threadIdx.x != 0 || blockIdx.x != 0) return;
    for (int c = 0; c < 2; ++c) {
        const float* wa = c ? w2a : w1a;
        const float* ba = c ? b2a : b1a;
        float* T = c ? t2 : t1;
        unsigned* M = c ? mask2 : mask1;
        float tt[NCONST]; int m = 0;
        for (int k = 0; k < NCONST; ++k) {
            if (wa[k] != 0.f) {
                float v = -ba[k] / wa[k];
                int p = m++;
                while (p > 0 && tt[p-1] > v) { tt[p] = tt[p-1]; --p; }
                tt[p] = v;
            }
        }
        for (int i = 0; i < m; ++i) T[i] = tt[i];
        meta[c] = m;
        for (int j = 0; j <= m; ++j) {
            float rep;
            if (m == 0)      rep = 0.f;
            else if (j == 0) rep = tt[0] - 1.f;
            else if (j == m) rep = tt[m-1] + 1.f;
            else             rep = 0.5f * (tt[j-1] + tt[j]);
            unsigned msk = 0;
            for (int k = 0; k < NCONST; ++k)
                if (rep * wa[k] + ba[k] > 0.f) msk |= (1u << k);
            M[j] = msk;
        }
    }
}

// U_s[idx] = sum_{k active} wa_k * wb[k,idx];  V_s[idx] = sum_{k active} ba_k * wb[k,idx] + bb[idx]
__global__ void build_uv_kernel(const float* wa, const float* ba,
                                const float* wb, const float* bb,
                                const unsigned* mask, const int* meta, int conv,
                                int size, float* U, float* V) {
    int seg = blockIdx.y;
    if (seg > meta[conv]) return;        // unused segment slots (ws is poisoned)
    int idx = blockIdx.x * blockDim.x + threadIdx.x;
    if (idx >= size) return;
    unsigned msk = mask[seg];
    float u = 0.f, v = 0.f;
    for (int k = 0; k < NCONST; ++k) {
        if (msk & (1u << k)) {
            float w = wb[k * size + idx];
            u = fmaf(wa[k], w, u);
            v = fmaf(ba[k], w, v);
        }
    }
    v += bb[idx];
    U[(size_t)seg * size + idx] = u;
    V[(size_t)seg * size + idx] = v;
}

// Fused per-edge message + scatter-max. One thread per (edge, out-channel).
template<int IC, int OC, int EPB>
__global__ void edge_kernel(const float* __restrict__ xin,
                            const int* __restrict__ src, const int* __restrict__ tgt,
                            const float* __restrict__ ea,
                            const float* __restrict__ t_arr, const int* __restrict__ meta, int conv,
                            const float* __restrict__ U, const float* __restrict__ V,
                            float* __restrict__ agg, int E) {
    int e = blockIdx.x * EPB + threadIdx.x / OC;
    int o = threadIdx.x % OC;
    if (e >= E) return;
    float a = ea[e];
    int m = meta[conv];
    int j = 0;
    for (int i = 0; i < m; ++i) j += (t_arr[i] < a) ? 1 : 0;
    const float* Us = U + (size_t)j * (IC * OC);
    const float* Vs = V + (size_t)j * (IC * OC);
    int s = src[e];
    float acc = 0.f;
#pragma unroll
    for (int i = 0; i < IC; ++i) {
        float xv = xin[s * IC + i];
        acc = fmaf(xv, fmaf(a, Us[i * OC + o], Vs[i * OC + o]), acc);
    }
    atomicMaxFloat(&agg[(size_t)tgt[e] * OC + o], acc);
}

// out = elu( fixup(agg) + x @ wroot + bias ), one thread per (node, channel)
template<int IC, int OC>
__global__ void node_kernel(const float* __restrict__ xin, const float* __restrict__ agg,
                            const float* __restrict__ wroot, const float* __restrict__ bias,
                            float* __restrict__ out, int N) {
    int idx = blockIdx.x * blockDim.x + threadIdx.x;
    if (idx >= N * OC) return;
    int n = idx / OC, c = idx % OC;
    float v = agg[idx];
    if (v == -FLT_MAX) v = 0.f;          // node with no in-edges -> 0
    float acc = v + bias[c];
#pragma unroll
    for (int i = 0; i < IC; ++i) acc = fmaf(xin[n * IC + i], wroot[i * OC + c], acc);
    out[idx] = acc > 0.f ? acc : expm1f(acc);
}

__global__ void fc1_kernel(const float* __restrict__ h2, const float* __restrict__ w,
                           const float* __restrict__ b, float* __restrict__ out, int N) {
    int idx = blockIdx.x * blockDim.x + threadIdx.x;
    if (idx >= N * 128) return;
    int n = idx >> 7, c = idx & 127;
    float acc = b[c];
#pragma unroll
    for (int i = 0; i < 64; ++i) acc = fmaf(h2[n * 64 + i], w[i * 128 + c], acc);
    out[idx] = acc > 0.f ? acc : expm1f(acc);
}

// One wave (64 lanes) per node: lanes 0..9 compute logits, shuffle-reduce logsumexp.
__global__ void fc2_kernel(const float* __restrict__ h3, const float* __restrict__ w,
                           const float* __restrict__ b, float* __restrict__ out, int N) {
    int n = blockIdx.x * (blockDim.x / 64) + threadIdx.x / 64;
    int o = threadIdx.x % 64;
    if (n >= N) return;
    float logit = -FLT_MAX;
    if (o < 10) {
        float acc = b[o];
#pragma unroll
        for (int i = 0; i < 128; ++i) acc = fmaf(h3[n * 128 + i], w[i * 10 + o], acc);
        logit = acc;
    }
    float mx = -FLT_MAX;
#pragma unroll
    for (int i = 0; i < 10; ++i) mx = fmaxf(mx, __shfl(logit, i, 64));
    float s = 0.f;
#pragma unroll
    for (int i = 0; i < 10; ++i) s += expf(__shfl(logit, i, 64) - mx);
    if (o < 10) out[n * 10 + o] = logit - mx - logf(s);
}

extern "C" void kernel_launch(void* const* d_in, const int* in_sizes, int n_in,
                              void* d_out, int out_size, void* d_ws, size_t ws_size,
                              hipStream_t stream) {
    const float* x     = (const float*)d_in[0];
    const int*   eidx  = (const int*)d_in[1];
    const float* ea    = (const float*)d_in[2];
    const float* w1a   = (const float*)d_in[3];
    const float* b1a   = (const float*)d_in[4];
    const float* w1b   = (const float*)d_in[5];
    const float* b1b   = (const float*)d_in[6];
    const float* wr1   = (const float*)d_in[7];
    const float* bias1 = (const float*)d_in[8];
    const float* w2a   = (const float*)d_in[9];
    const float* b2a   = (const float*)d_in[10];
    const float* w2b   = (const float*)d_in[11];
    const float* b2b   = (const float*)d_in[12];
    const float* wr2   = (const float*)d_in[13];
    const float* bias2 = (const float*)d_in[14];
    const float* fc1w  = (const float*)d_in[15];
    const float* fc1b  = (const float*)d_in[16];
    const float* fc2w  = (const float*)d_in[17];
    const float* fc2b  = (const float*)d_in[18];

    const int N = in_sizes[0] / 16;   // 20000
    const int E = in_sizes[2];        // 100000
    const int* src = eidx;
    const int* tgt = eidx + E;

    float* ws = (float*)d_ws;
    size_t off = 0;
    int*      meta = (int*)(ws + off);      off += 16;
    float*    T1   = ws + off;              off += 32;
    float*    T2   = ws + off;              off += 32;
    unsigned* M1   = (unsigned*)(ws + off); off += 32;
    unsigned* M2   = (unsigned*)(ws + off); off += 32;
    float*    U1   = ws + off;              off += 26 * 512;
    float*    V1   = ws + off;              off += 26 * 512;
    float*    U2   = ws + off;              off += 26 * 2048;
    float*    V2   = ws + off;              off += 26 * 2048;
    float*    AGG1 = ws + off;              off += (size_t)N * 32;
    float*    AGG2 = ws + off;              off += (size_t)N * 64;   // contiguous with AGG1
    float*    H1   = ws + off;              off += (size_t)N * 32;
    float*    H2   = ws + off;              off += (size_t)N * 64;
    float*    H3   = ws + off;              off += (size_t)N * 128;

    // 1. init both agg buffers (contiguous) to -FLT_MAX
    fill_neg_kernel<<<512, 256, 0, stream>>>(AGG1, N * 96);
    // 2. breakpoints + segment masks
    prep_kernel<<<1, 64, 0, stream>>>(w1a, b1a, w2a, b2a, meta, T1, T2, M1, M2);
    // 3. per-segment U/V for both convs
    build_uv_kernel<<<dim3(2, 26), 256, 0, stream>>>(w1a, b1a, w1b, b1b, M1, meta, 0, 512,  U1, V1);
    build_uv_kernel<<<dim3(8, 26), 256, 0, stream>>>(w2a, b2a, w2b, b2b, M2, meta, 1, 2048, U2, V2);
    // 4. conv1: per-edge msg + scatter-max, then node update
    edge_kernel<16, 32, 8><<<(E + 7) / 8, 256, 0, stream>>>(x, src, tgt, ea, T1, meta, 0, U1, V1, AGG1, E);
    node_kernel<16, 32><<<(N * 32 + 255) / 256, 256, 0, stream>>>(x, AGG1, wr1, bias1, H1, N);
    // 5. conv2
    edge_kernel<32, 64, 4><<<(E + 3) / 4, 256, 0, stream>>>(H1, src, tgt, ea, T2, meta, 1, U2, V2, AGG2, E);
    node_kernel<32, 64><<<(N * 64 + 255) / 256, 256, 0, stream>>>(H1, AGG2, wr2, bias2, H2, N);
    // 6. trailing FCs + log_softmax
    fc1_kernel<<<(N * 128 + 255) / 256, 256, 0, stream>>>(H2, fc1w, fc1b, H3, N);
    fc2_kernel<<<(N + 3) / 4, 256, 0, stream>>>(H3, fc2w, fc2b, (float*)d_out, N);
}

// Round 2
// 331.140 us; speedup vs baseline: 1.0287x; 1.0287x over previous
//
#include <hip/hip_runtime.h>
#include <float.h>
#include <math.h>

// NNConv net: 2x edge-conditioned conv (scalar edge attr) + 2 FC + log_softmax.
// Edge MLP input is a SCALAR a_e -> generated weight matrix is piecewise-linear
// in a_e: W_e = a_e*U_s + V_s over <=26 breakpoint segments. We bucket edges by
// segment and register-cache U_s/V_s per wave (lane = output channel), so per
// edge the wave does only 2*IC FMAs/lane and one atomic-max row scatter.

#define NCONST 25
#define CH1 64   // edges per wave chunk, conv1
#define CH2 32   // edges per wave chunk, conv2
#define PACK_MASK 0x1FFFF  // edge id < 2^17 (E = 100000)

__device__ __forceinline__ void atomicMaxFloat(float* addr, float val) {
    if (val >= 0.f) atomicMax((int*)addr, __float_as_int(val));
    else            atomicMin((unsigned int*)addr, __float_as_uint(val));
}

// Fill: agg regions with -FLT_MAX, order arrays with -1, hist with 0.
__global__ void fill_kernel(float* agg, int nAgg, int* ords, int nOrd, int* hist, int nH) {
    int i = blockIdx.x * blockDim.x + threadIdx.x;
    int stride = gridDim.x * blockDim.x;
    int total = nAgg + nOrd + nH;
    for (; i < total; i += stride) {
        if (i < nAgg) agg[i] = -FLT_MAX;
        else if (i < nAgg + nOrd) ords[i - nAgg] = -1;
        else hist[i - nAgg - nOrd] = 0;
    }
}

// Per edge: segment rank for both convs (j = #breakpoints < a, no sort needed),
// LDS-aggregated histograms, store packed (j1 | j2<<8).
__global__ void assign_hist_kernel(const float* __restrict__ ea,
                                   const float* __restrict__ w1a, const float* __restrict__ b1a,
                                   const float* __restrict__ w2a, const float* __restrict__ b2a,
                                   int E, int* __restrict__ segpack, int* __restrict__ hist) {
    __shared__ float t1[NCONST], t2[NCONST];
    __shared__ int lh[64];
    int tid = threadIdx.x;
    if (tid < NCONST) {
        float w = w1a[tid]; t1[tid] = (w != 0.f) ? (-b1a[tid] / w) : INFINITY;
        float v = w2a[tid]; t2[tid] = (v != 0.f) ? (-b2a[tid] / v) : INFINITY;
    }
    if (tid < 64) lh[tid] = 0;
    __syncthreads();
    int e = blockIdx.x * blockDim.x + tid;
    int j1 = 0, j2 = 0;
    bool valid = e < E;
    if (valid) {
        float a = ea[e];
        for (int k = 0; k < NCONST; ++k) { j1 += (t1[k] < a); j2 += (t2[k] < a); }
        segpack[e] = j1 | (j2 << 8);
        atomicAdd(&lh[j1], 1); atomicAdd(&lh[32 + j2], 1);
    }
    __syncthreads();
    if (tid < 64 && lh[tid]) atomicAdd(&hist[tid], lh[tid]);
}

// Single thread: chunk-aligned bucket offsets (pads guarantee a wave chunk
// never spans two segments).
__global__ void scanpad_kernel(const int* hist, int* cur) {
    if (threadIdx.x != 0 || blockIdx.x != 0) return;
    int off = 0;
    for (int j = 0; j < 26; ++j) { cur[j] = off; off += ((hist[j] + CH1 - 1) / CH1) * CH1; }
    off = 0;
    for (int j = 0; j < 26; ++j) { cur[32 + j] = off; off += ((hist[32 + j] + CH2 - 1) / CH2) * CH2; }
}

// Block-aggregated scatter: LDS rank + one global atomicAdd per (block,bin).
__global__ void scatter_kernel(const int* __restrict__ segpack, int E, int* __restrict__ cur,
                               int* __restrict__ order1, int* __restrict__ order2) {
    __shared__ int lh[64], lb[64];
    int tid = threadIdx.x;
    if (tid < 64) lh[tid] = 0;
    __syncthreads();
    int e = blockIdx.x * blockDim.x + tid;
    bool valid = e < E;
    int j1 = 0, j2 = 0, r1 = 0, r2 = 0;
    if (valid) {
        int p = segpack[e]; j1 = p & 0xFF; j2 = p >> 8;
        r1 = atomicAdd(&lh[j1], 1); r2 = atomicAdd(&lh[32 + j2], 1);
    }
    __syncthreads();
    if (tid < 64 && lh[tid]) lb[tid] = atomicAdd(&cur[tid], lh[tid]);
    __syncthreads();
    if (valid) {
        order1[lb[j1] + r1] = (j1 << 17) | e;
        order2[lb[32 + j2] + r2] = (j2 << 17) | e;
    }
}

// Single thread: sorted breakpoints + per-segment relu-active masks.
__global__ void prep_kernel(const float* w1a, const float* b1a,
                            const float* w2a, const float* b2a,
                            int* meta, unsigned* mask1, unsigned* mask2) {
    if (threadIdx.x != 0 || blockIdx.x != 0) return;
    for (int c = 0; c < 2; ++c) {
        const float* wa = c ? w2a : w1a;
        const float* ba = c ? b2a : b1a;
        unsigned* M = c ? mask2 : mask1;
        float tt[NCONST]; int m = 0;
        for (int k = 0; k < NCONST; ++k) {
            if (wa[k] != 0.f) {
                float v = -ba[k] / wa[k];
                int p = m++;
                while (p > 0 && tt[p-1] > v) { tt[p] = tt[p-1]; --p; }
                tt[p] = v;
            }
        }
        meta[c] = m;
        for (int j = 0; j <= m; ++j) {
            float rep;
            if (m == 0)      rep = 0.f;
            else if (j == 0) rep = tt[0] - 1.f;
            else if (j == m) rep = tt[m-1] + 1.f;
            else             rep = 0.5f * (tt[j-1] + tt[j]);
            unsigned msk = 0;
            for (int k = 0; k < NCONST; ++k)
                if (rep * wa[k] + ba[k] > 0.f) msk |= (1u << k);
            M[j] = msk;
        }
    }
}

// U_s = sum_{k active} wa_k*wb_k ; V_s = sum_{k active} ba_k*wb_k + bb. Both convs.
__global__ void build_uv_fused(const float* w1a, const float* b1a, const float* w1b, const float* b1b,
                               const float* w2a, const float* b2a, const float* w2b, const float* b2b,
                               const unsigned* M1, const unsigned* M2, const int* meta,
                               float* U1, float* V1, float* U2, float* V2) {
    int seg = blockIdx.y;
    int bx = blockIdx.x;
    if (bx < 2) {
        if (seg > meta[0]) return;
        int idx = bx * 256 + threadIdx.x;           // < 512
        unsigned msk = M1[seg];
        float u = 0.f, v = 0.f;
        for (int k = 0; k < NCONST; ++k)
            if (msk & (1u << k)) { float w = w1b[k * 512 + idx]; u = fmaf(w1a[k], w, u); v = fmaf(b1a[k], w, v); }
        v += b1b[idx];
        U1[seg * 512 + idx] = u; V1[seg * 512 + idx] = v;
    } else {
        if (seg > meta[1]) return;
        int idx = (bx - 2) * 256 + threadIdx.x;     // < 2048
        unsigned msk = M2[seg];
        float u = 0.f, v = 0.f;
        for (int k = 0; k < NCONST; ++k)
            if (msk & (1u << k)) { float w = w2b[k * 2048 + idx]; u = fmaf(w2a[k], w, u); v = fmaf(b2a[k], w, v); }
        v += b2b[idx];
        U2[seg * 2048 + idx] = u; V2[seg * 2048 + idx] = v;
    }
}

// conv1 edge kernel: IC=16, OC=32. Two edges per wave (lane<32: edge A, else B),
// U/V columns register-cached per wave (same for both halves).
__global__ void edge1_kernel(const float* __restrict__ xin, const int* __restrict__ src,
                             const int* __restrict__ tgt, const float* __restrict__ ea,
                             const int* __restrict__ order,
                             const float* __restrict__ U, const float* __restrict__ V,
                             float* __restrict__ agg) {
    int wave = __builtin_amdgcn_readfirstlane((blockIdx.x * blockDim.x + threadIdx.x) >> 6);
    int lane = threadIdx.x & 63;
    int base = wave * CH1;
    int half = lane >> 5, c = lane & 31;
    float Ur[16], Vr[16];
    int cur_seg = -1;
    for (int t = 0; t < CH1; t += 2) {
        int pA = __builtin_amdgcn_readfirstlane(order[base + t]);
        if (pA < 0) break;                         // bucket-tail pads
        int pB = __builtin_amdgcn_readfirstlane(order[base + t + 1]);
        int seg = pA >> 17;
        if (seg != cur_seg) {
            cur_seg = seg;
            const float* Us = U + seg * 512 + c;
            const float* Vs = V + seg * 512 + c;
#pragma unroll
            for (int i = 0; i < 16; ++i) { Ur[i] = Us[i * 32]; Vr[i] = Vs[i * 32]; }
        }
        bool vB = pB >= 0;
        int eA = pA & PACK_MASK;
        int eB = vB ? (pB & PACK_MASK) : eA;
        int sA = src[eA], sB = src[eB];
        int tA = tgt[eA], tB = tgt[eB];
        float aA = ea[eA], aB = ea[eB];
        const float* xA = xin + sA * 16;
        const float* xB = xin + sB * 16;
        float ah = half ? aB : aA;
        int   th = half ? tB : tA;
        float acc = 0.f;
#pragma unroll
        for (int i = 0; i < 16; ++i) {
            float xi = half ? xB[i] : xA[i];       // uniform-per-half scalar values
            acc = fmaf(xi, fmaf(ah, Ur[i], Vr[i]), acc);
        }
        if (!half || vB) atomicMaxFloat(&agg[th * 32 + c], acc);
    }
}

// conv2 edge kernel: IC=32, OC=64. One edge per wave iteration x2 (A/B pair for
// ILP), lane = output channel, U/V columns register-cached.
__global__ void edge2_kernel(const float* __restrict__ xin, const int* __restrict__ src,
                             const int* __restrict__ tgt, const float* __restrict__ ea,
                             const int* __restrict__ order,
                             const float* __restrict__ U, const float* __restrict__ V,
                             float* __restrict__ agg) {
    int wave = __builtin_amdgcn_readfirstlane((blockIdx.x * blockDim.x + threadIdx.x) >> 6);
    int lane = threadIdx.x & 63;
    int base = wave * CH2;
    float Ur[32], Vr[32];
    int cur_seg = -1;
    for (int t = 0; t < CH2; t += 2) {
        int pA = __builtin_amdgcn_readfirstlane(order[base + t]);
        if (pA < 0) break;
        int pB = __builtin_amdgcn_readfirstlane(order[base + t + 1]);
        int seg = pA >> 17;
        if (seg != cur_seg) {
            cur_seg = seg;
            const float* Us = U + seg * 2048 + lane;
            const float* Vs = V + seg * 2048 + lane;
#pragma unroll
            for (int i = 0; i < 32; ++i) { Ur[i] = Us[i * 64]; Vr[i] = Vs[i * 64]; }
        }
        bool vB = pB >= 0;
        int eA = pA & PACK_MASK;
        int eB = vB ? (pB & PACK_MASK) : eA;
        int sA = src[eA], sB = src[eB];
        int tA = tgt[eA], tB = tgt[eB];
        float aA = ea[eA], aB = ea[eB];
        const float* xA = xin + sA * 32;
        const float* xB = xin + sB * 32;
        float accA = 0.f, accB = 0.f;
#pragma unroll
        for (int i = 0; i < 32; ++i) {
            accA = fmaf(xA[i], fmaf(aA, Ur[i], Vr[i]), accA);
            accB = fmaf(xB[i], fmaf(aB, Ur[i], Vr[i]), accB);
        }
        atomicMaxFloat(&agg[tA * 64 + lane], accA);
        if (vB) atomicMaxFloat(&agg[tB * 64 + lane], accB);
    }
}

// out = elu( fixup(agg) + x @ wroot + bias )
template<int IC, int OC>
__global__ void node_kernel(const float* __restrict__ xin, const float* __restrict__ agg,
                            const float* __restrict__ wroot, const float* __restrict__ bias,
                            float* __restrict__ out, int N) {
    int idx = blockIdx.x * blockDim.x + threadIdx.x;
    if (idx >= N * OC) return;
    int n = idx / OC, c = idx % OC;
    float v = agg[idx];
    if (v == -FLT_MAX) v = 0.f;
    float acc = v + bias[c];
#pragma unroll
    for (int i = 0; i < IC; ++i) acc = fmaf(xin[n * IC + i], wroot[i * OC + c], acc);
    out[idx] = acc > 0.f ? acc : expm1f(acc);
}

__global__ void fc1_kernel(const float* __restrict__ h2, const float* __restrict__ w,
                           const float* __restrict__ b, float* __restrict__ out, int N) {
    int idx = blockIdx.x * blockDim.x + threadIdx.x;
    if (idx >= N * 128) return;
    int n = idx >> 7, c = idx & 127;
    float acc = b[c];
#pragma unroll
    for (int i = 0; i < 64; ++i) acc = fmaf(h2[n * 64 + i], w[i * 128 + c], acc);
    out[idx] = acc > 0.f ? acc : expm1f(acc);
}

__global__ void fc2_kernel(const float* __restrict__ h3, const float* __restrict__ w,
                           const float* __restrict__ b, float* __restrict__ out, int N) {
    int n = blockIdx.x * (blockDim.x / 64) + threadIdx.x / 64;
    int o = threadIdx.x % 64;
    if (n >= N) return;
    float logit = -FLT_MAX;
    if (o < 10) {
        float acc = b[o];
#pragma unroll
        for (int i = 0; i < 128; ++i) acc = fmaf(h3[n * 128 + i], w[i * 10 + o], acc);
        logit = acc;
    }
    float mx = -FLT_MAX;
#pragma unroll
    for (int i = 0; i < 10; ++i) mx = fmaxf(mx, __shfl(logit, i, 64));
    float s = 0.f;
#pragma unroll
    for (int i = 0; i < 10; ++i) s += expf(__shfl(logit, i, 64) - mx);
    if (o < 10) out[n * 10 + o] = logit - mx - logf(s);
}

extern "C" void kernel_launch(void* const* d_in, const int* in_sizes, int n_in,
                              void* d_out, int out_size, void* d_ws, size_t ws_size,
                              hipStream_t stream) {
    const float* x     = (const float*)d_in[0];
    const int*   eidx  = (const int*)d_in[1];
    const float* ea    = (const float*)d_in[2];
    const float* w1a   = (const float*)d_in[3];
    const float* b1a   = (const float*)d_in[4];
    const float* w1b   = (const float*)d_in[5];
    const float* b1b   = (const float*)d_in[6];
    const float* wr1   = (const float*)d_in[7];
    const float* bias1 = (const float*)d_in[8];
    const float* w2a   = (const float*)d_in[9];
    const float* b2a   = (const float*)d_in[10];
    const float* w2b   = (const float*)d_in[11];
    const float* b2b   = (const float*)d_in[12];
    const float* wr2   = (const float*)d_in[13];
    const float* bias2 = (const float*)d_in[14];
    const float* fc1w  = (const float*)d_in[15];
    const float* fc1b  = (const float*)d_in[16];
    const float* fc2w  = (const float*)d_in[17];
    const float* fc2b  = (const float*)d_in[18];

    const int N = in_sizes[0] / 16;   // 20000
    const int E = in_sizes[2];        // 100000
    const int* src = eidx;
    const int* tgt = eidx + E;

    const int cap1 = ((E + 26 * (CH1 - 1)) + CH1 - 1) / CH1 * CH1;   // 101696
    const int cap2 = ((E + 26 * (CH2 - 1)) + CH2 - 1) / CH2 * CH2;   // 100832

    float* ws = (float*)d_ws;
    size_t off = 0;
    int*      meta = (int*)(ws + off);      off += 16;
    unsigned* M1   = (unsigned*)(ws + off); off += 32;
    unsigned* M2   = (unsigned*)(ws + off); off += 32;
    int*      hist = (int*)(ws + off);      off += 64;
    int*      cur  = (int*)(ws + off);      off += 64;
    int*      segp = (int*)(ws + off);      off += E;
    int*      ord1 = (int*)(ws + off);      off += cap1;   // ord1/ord2 contiguous
    int*      ord2 = (int*)(ws + off);      off += cap2;
    float*    U1   = ws + off;              off += 26 * 512;
    float*    V1   = ws + off;              off += 26 * 512;
    float*    U2   = ws + off;              off += 26 * 2048;
    float*    V2   = ws + off;              off += 26 * 2048;
    float*    AGG1 = ws + off;              off += (size_t)N * 32;   // AGG1/AGG2 contiguous
    float*    AGG2 = ws + off;              off += (size_t)N * 64;
    float*    H1b  = ws + off;              off += (size_t)N * 32;
    float*    H2b  = ws + off;              off += (size_t)N * 64;
    float*    H3b  = ws + off;              off += (size_t)N * 128;

    // 1. init: agg=-FLT_MAX, order arrays=-1, hist=0
    fill_kernel<<<512, 256, 0, stream>>>(AGG1, N * 96, ord1, cap1 + cap2, hist, 64);
    // 2. per-edge segment ranks + histograms
    assign_hist_kernel<<<(E + 255) / 256, 256, 0, stream>>>(ea, w1a, b1a, w2a, b2a, E, segp, hist);
    // 3. chunk-aligned bucket offsets
    scanpad_kernel<<<1, 64, 0, stream>>>(hist, cur);
    // 4. breakpoint sort + segment masks (independent of 2-3)
    prep_kernel<<<1, 64, 0, stream>>>(w1a, b1a, w2a, b2a, meta, M1, M2);
    // 5. scatter edges into segment-sorted order arrays
    scatter_kernel<<<(E + 255) / 256, 256, 0, stream>>>(segp, E, cur, ord1, ord2);
    // 6. per-segment U/V tables, both convs
    build_uv_fused<<<dim3(10, 26), 256, 0, stream>>>(w1a, b1a, w1b, b1b, w2a, b2a, w2b, b2b,
                                                     M1, M2, meta, U1, V1, U2, V2);
    // 7. conv1
    edge1_kernel<<<(cap1 / CH1 + 3) / 4, 256, 0, stream>>>(x, src, tgt, ea, ord1, U1, V1, AGG1);
    node_kernel<16, 32><<<(N * 32 + 255) / 256, 256, 0, stream>>>(x, AGG1, wr1, bias1, H1b, N);
    // 8. conv2
    edge2_kernel<<<(cap2 / CH2 + 3) / 4, 256, 0, stream>>>(H1b, src, tgt, ea, ord2, U2, V2, AGG2);
    node_kernel<32, 64><<<(N * 64 + 255) / 256, 256, 0, stream>>>(H1b, AGG2, wr2, bias2, H2b, N);
    // 9. trailing FCs + log_softmax
    fc1_kernel<<<(N * 128 + 255) / 256, 256, 0, stream>>>(H2b, fc1w, fc1b, H3b, N);
    fc2_kernel<<<(N + 3) / 4, 256, 0, stream>>>(H3b, fc2w, fc2b, (float*)d_out, N);
}

// Round 3
// 295.664 us; speedup vs baseline: 1.1521x; 1.1200x over previous
//
#include <hip/hip_runtime.h>
#include <float.h>
#include <math.h>

// NNConv net: 2x edge-conditioned conv (scalar edge attr) + 2 FC + log_softmax.
// Edge MLP input is a SCALAR a_e -> generated weight matrix is piecewise-linear
// in a_e: W_e = a_e*U_s + V_s over <=26 breakpoint segments. We bucket edges by
// segment and register-cache U_s/V_s per wave (lane = output channel), so per
// edge the wave does only 2*IC FMAs/lane and one atomic-max row scatter.
// R2: killed the single-thread prep_kernel (56us of serial global latency) --
// masks are computed rank-wise (no sort) inside each build_uv block; scanpad
// loads hist through LDS in parallel.

#define NCONST 25
#define CH1 64   // edges per wave chunk, conv1
#define CH2 32   // edges per wave chunk, conv2
#define PACK_MASK 0x1FFFF  // edge id < 2^17 (E = 100000)

__device__ __forceinline__ void atomicMaxFloat(float* addr, float val) {
    if (val >= 0.f) atomicMax((int*)addr, __float_as_int(val));
    else            atomicMin((unsigned int*)addr, __float_as_uint(val));
}

// Fill: agg regions with -FLT_MAX, order arrays with -1, hist with 0.
__global__ void fill_kernel(float* agg, int nAgg, int* ords, int nOrd, int* hist, int nH) {
    int i = blockIdx.x * blockDim.x + threadIdx.x;
    int stride = gridDim.x * blockDim.x;
    int total = nAgg + nOrd + nH;
    for (; i < total; i += stride) {
        if (i < nAgg) agg[i] = -FLT_MAX;
        else if (i < nAgg + nOrd) ords[i - nAgg] = -1;
        else hist[i - nAgg - nOrd] = 0;
    }
}

// Per edge: segment rank for both convs (j = #breakpoints < a, no sort needed),
// LDS-aggregated histograms, store packed (j1 | j2<<8).
__global__ void assign_hist_kernel(const float* __restrict__ ea,
                                   const float* __restrict__ w1a, const float* __restrict__ b1a,
                                   const float* __restrict__ w2a, const float* __restrict__ b2a,
                                   int E, int* __restrict__ segpack, int* __restrict__ hist) {
    __shared__ float t1[NCONST], t2[NCONST];
    __shared__ int lh[64];
    int tid = threadIdx.x;
    if (tid < NCONST) {
        float w = w1a[tid]; t1[tid] = (w != 0.f) ? (-b1a[tid] / w) : INFINITY;
        float v = w2a[tid]; t2[tid] = (v != 0.f) ? (-b2a[tid] / v) : INFINITY;
    }
    if (tid < 64) lh[tid] = 0;
    __syncthreads();
    int e = blockIdx.x * blockDim.x + tid;
    bool valid = e < E;
    if (valid) {
        float a = ea[e];
        int j1 = 0, j2 = 0;
        for (int k = 0; k < NCONST; ++k) { j1 += (t1[k] < a); j2 += (t2[k] < a); }
        segpack[e] = j1 | (j2 << 8);
        atomicAdd(&lh[j1], 1); atomicAdd(&lh[32 + j2], 1);
    }
    __syncthreads();
    if (tid < 64 && lh[tid]) atomicAdd(&hist[tid], lh[tid]);
}

// Parallel hist load through LDS, then two lanes do the 26-step chunk-aligned
// exclusive scan LDS-resident (no serial global-latency chain).
__global__ void scanpad_kernel(const int* __restrict__ hist, int* __restrict__ cur) {
    __shared__ int h[64];
    int tid = threadIdx.x;
    h[tid] = hist[tid];
    __syncthreads();
    if (tid == 0) {
        int off = 0;
        for (int j = 0; j < 26; ++j) { cur[j] = off; off += ((h[j] + CH1 - 1) / CH1) * CH1; }
    } else if (tid == 1) {
        int off = 0;
        for (int j = 0; j < 26; ++j) { cur[32 + j] = off; off += ((h[32 + j] + CH2 - 1) / CH2) * CH2; }
    }
}

// Block-aggregated scatter: LDS rank + one global atomicAdd per (block,bin).
__global__ void scatter_kernel(const int* __restrict__ segpack, int E, int* __restrict__ cur,
                               int* __restrict__ order1, int* __restrict__ order2) {
    __shared__ int lh[64], lb[64];
    int tid = threadIdx.x;
    if (tid < 64) lh[tid] = 0;
    __syncthreads();
    int e = blockIdx.x * blockDim.x + tid;
    bool valid = e < E;
    int j1 = 0, j2 = 0, r1 = 0, r2 = 0;
    if (valid) {
        int p = segpack[e]; j1 = p & 0xFF; j2 = p >> 8;
        r1 = atomicAdd(&lh[j1], 1); r2 = atomicAdd(&lh[32 + j2], 1);
    }
    __syncthreads();
    if (tid < 64 && lh[tid]) lb[tid] = atomicAdd(&cur[tid], lh[tid]);
    __syncthreads();
    if (valid) {
        order1[lb[j1] + r1] = (j1 << 17) | e;
        order2[lb[32 + j2] + r2] = (j2 << 17) | e;
    }
}

// U_s = sum_{k active} wa_k*wb_k ; V_s = sum_{k active} ba_k*wb_k + bb.
// Per-block rank-based mask computation (LDS-resident, no sort, no prep kernel):
// unit k active in segment j iff wa>0: j>r_k; wa<0: j<=r_k; wa==0: ba>0,
// where r_k = #{l: t_l < t_k}. Tie segments are phantom (no edge ranks there).
__global__ void build_uv_fused(const float* w1a, const float* b1a, const float* w1b, const float* b1b,
                               const float* w2a, const float* b2a, const float* w2b, const float* b2b,
                               float* U1, float* V1, float* U2, float* V2) {
    __shared__ float swa[NCONST], sba[NCONST], st[NCONST];
    __shared__ int sr[NCONST];
    __shared__ unsigned msk_sh;
    int seg = blockIdx.y;
    int bx = blockIdx.x;
    int conv = (bx < 2) ? 0 : 1;
    const float* wa = conv ? w2a : w1a;
    const float* ba = conv ? b2a : b1a;
    int tid = threadIdx.x;
    if (tid < NCONST) {
        float w = wa[tid], b = ba[tid];
        swa[tid] = w; sba[tid] = b;
        st[tid] = (w != 0.f) ? (-b / w) : INFINITY;
    }
    __syncthreads();
    if (tid < NCONST) {
        int rk = 0;
        for (int l = 0; l < NCONST; ++l) rk += (st[l] < st[tid]) ? 1 : 0;
        sr[tid] = rk;
    }
    __syncthreads();
    if (tid == 0) {
        unsigned m = 0;
        for (int k = 0; k < NCONST; ++k) {
            float w = swa[k];
            bool act = (w > 0.f) ? (seg > sr[k])
                     : (w < 0.f) ? (seg <= sr[k])
                                 : (sba[k] > 0.f);
            if (act) m |= (1u << k);
        }
        msk_sh = m;
    }
    __syncthreads();
    unsigned msk = msk_sh;
    if (conv == 0) {
        int idx = bx * 256 + tid;           // < 512
        float u = 0.f, v = 0.f;
        for (int k = 0; k < NCONST; ++k)
            if (msk & (1u << k)) { float w = w1b[k * 512 + idx]; u = fmaf(swa[k], w, u); v = fmaf(sba[k], w, v); }
        v += b1b[idx];
        U1[seg * 512 + idx] = u; V1[seg * 512 + idx] = v;
    } else {
        int idx = (bx - 2) * 256 + tid;     // < 2048
        float u = 0.f, v = 0.f;
        for (int k = 0; k < NCONST; ++k)
            if (msk & (1u << k)) { float w = w2b[k * 2048 + idx]; u = fmaf(swa[k], w, u); v = fmaf(sba[k], w, v); }
        v += b2b[idx];
        U2[seg * 2048 + idx] = u; V2[seg * 2048 + idx] = v;
    }
}

// conv1 edge kernel: IC=16, OC=32. Two edges per wave (lane<32: edge A, else B),
// U/V columns register-cached per wave (same for both halves).
__global__ void edge1_kernel(const float* __restrict__ xin, const int* __restrict__ src,
                             const int* __restrict__ tgt, const float* __restrict__ ea,
                             const int* __restrict__ order,
                             const float* __restrict__ U, const float* __restrict__ V,
                             float* __restrict__ agg) {
    int wave = __builtin_amdgcn_readfirstlane((blockIdx.x * blockDim.x + threadIdx.x) >> 6);
    int lane = threadIdx.x & 63;
    int base = wave * CH1;
    int half = lane >> 5, c = lane & 31;
    float Ur[16], Vr[16];
    int cur_seg = -1;
    for (int t = 0; t < CH1; t += 2) {
        int pA = __builtin_amdgcn_readfirstlane(order[base + t]);
        if (pA < 0) break;                         // bucket-tail pads
        int pB = __builtin_amdgcn_readfirstlane(order[base + t + 1]);
        int seg = pA >> 17;
        if (seg != cur_seg) {
            cur_seg = seg;
            const float* Us = U + seg * 512 + c;
            const float* Vs = V + seg * 512 + c;
#pragma unroll
            for (int i = 0; i < 16; ++i) { Ur[i] = Us[i * 32]; Vr[i] = Vs[i * 32]; }
        }
        bool vB = pB >= 0;
        int eA = pA & PACK_MASK;
        int eB = vB ? (pB & PACK_MASK) : eA;
        int sA = src[eA], sB = src[eB];
        int tA = tgt[eA], tB = tgt[eB];
        float aA = ea[eA], aB = ea[eB];
        const float* xA = xin + sA * 16;
        const float* xB = xin + sB * 16;
        float ah = half ? aB : aA;
        int   th = half ? tB : tA;
        float acc = 0.f;
#pragma unroll
        for (int i = 0; i < 16; ++i) {
            float xi = half ? xB[i] : xA[i];
            acc = fmaf(xi, fmaf(ah, Ur[i], Vr[i]), acc);
        }
        if (!half || vB) atomicMaxFloat(&agg[th * 32 + c], acc);
    }
}

// conv2 edge kernel: IC=32, OC=64. A/B edge pair per iteration for ILP,
// lane = output channel, U/V columns register-cached.
__global__ void edge2_kernel(const float* __restrict__ xin, const int* __restrict__ src,
                             const int* __restrict__ tgt, const float* __restrict__ ea,
                             const int* __restrict__ order,
                             const float* __restrict__ U, const float* __restrict__ V,
                             float* __restrict__ agg) {
    int wave = __builtin_amdgcn_readfirstlane((blockIdx.x * blockDim.x + threadIdx.x) >> 6);
    int lane = threadIdx.x & 63;
    int base = wave * CH2;
    float Ur[32], Vr[32];
    int cur_seg = -1;
    for (int t = 0; t < CH2; t += 2) {
        int pA = __builtin_amdgcn_readfirstlane(order[base + t]);
        if (pA < 0) break;
        int pB = __builtin_amdgcn_readfirstlane(order[base + t + 1]);
        int seg = pA >> 17;
        if (seg != cur_seg) {
            cur_seg = seg;
            const float* Us = U + seg * 2048 + lane;
            const float* Vs = V + seg * 2048 + lane;
#pragma unroll
            for (int i = 0; i < 32; ++i) { Ur[i] = Us[i * 64]; Vr[i] = Vs[i * 64]; }
        }
        bool vB = pB >= 0;
        int eA = pA & PACK_MASK;
        int eB = vB ? (pB & PACK_MASK) : eA;
        int sA = src[eA], sB = src[eB];
        int tA = tgt[eA], tB = tgt[eB];
        float aA = ea[eA], aB = ea[eB];
        const float* xA = xin + sA * 32;
        const float* xB = xin + sB * 32;
        float accA = 0.f, accB = 0.f;
#pragma unroll
        for (int i = 0; i < 32; ++i) {
            accA = fmaf(xA[i], fmaf(aA, Ur[i], Vr[i]), accA);
            accB = fmaf(xB[i], fmaf(aB, Ur[i], Vr[i]), accB);
        }
        atomicMaxFloat(&agg[tA * 64 + lane], accA);
        if (vB) atomicMaxFloat(&agg[tB * 64 + lane], accB);
    }
}

// out = elu( fixup(agg) + x @ wroot + bias )
template<int IC, int OC>
__global__ void node_kernel(const float* __restrict__ xin, const float* __restrict__ agg,
                            const float* __restrict__ wroot, const float* __restrict__ bias,
                            float* __restrict__ out, int N) {
    int idx = blockIdx.x * blockDim.x + threadIdx.x;
    if (idx >= N * OC) return;
    int n = idx / OC, c = idx % OC;
    float v = agg[idx];
    if (v == -FLT_MAX) v = 0.f;
    float acc = v + bias[c];
#pragma unroll
    for (int i = 0; i < IC; ++i) acc = fmaf(xin[n * IC + i], wroot[i * OC + c], acc);
    out[idx] = acc > 0.f ? acc : expm1f(acc);
}

__global__ void fc1_kernel(const float* __restrict__ h2, const float* __restrict__ w,
                           const float* __restrict__ b, float* __restrict__ out, int N) {
    int idx = blockIdx.x * blockDim.x + threadIdx.x;
    if (idx >= N * 128) return;
    int n = idx >> 7, c = idx & 127;
    float acc = b[c];
#pragma unroll
    for (int i = 0; i < 64; ++i) acc = fmaf(h2[n * 64 + i], w[i * 128 + c], acc);
    out[idx] = acc > 0.f ? acc : expm1f(acc);
}

__global__ void fc2_kernel(const float* __restrict__ h3, const float* __restrict__ w,
                           const float* __restrict__ b, float* __restrict__ out, int N) {
    int n = blockIdx.x * (blockDim.x / 64) + threadIdx.x / 64;
    int o = threadIdx.x % 64;
    if (n >= N) return;
    float logit = -FLT_MAX;
    if (o < 10) {
        float acc = b[o];
#pragma unroll
        for (int i = 0; i < 128; ++i) acc = fmaf(h3[n * 128 + i], w[i * 10 + o], acc);
        logit = acc;
    }
    float mx = -FLT_MAX;
#pragma unroll
    for (int i = 0; i < 10; ++i) mx = fmaxf(mx, __shfl(logit, i, 64));
    float s = 0.f;
#pragma unroll
    for (int i = 0; i < 10; ++i) s += expf(__shfl(logit, i, 64) - mx);
    if (o < 10) out[n * 10 + o] = logit - mx - logf(s);
}

extern "C" void kernel_launch(void* const* d_in, const int* in_sizes, int n_in,
                              void* d_out, int out_size, void* d_ws, size_t ws_size,
                              hipStream_t stream) {
    const float* x     = (const float*)d_in[0];
    const int*   eidx  = (const int*)d_in[1];
    const float* ea    = (const float*)d_in[2];
    const float* w1a   = (const float*)d_in[3];
    const float* b1a   = (const float*)d_in[4];
    const float* w1b   = (const float*)d_in[5];
    const float* b1b   = (const float*)d_in[6];
    const float* wr1   = (const float*)d_in[7];
    const float* bias1 = (const float*)d_in[8];
    const float* w2a   = (const float*)d_in[9];
    const float* b2a   = (const float*)d_in[10];
    const float* w2b   = (const float*)d_in[11];
    const float* b2b   = (const float*)d_in[12];
    const float* wr2   = (const float*)d_in[13];
    const float* bias2 = (const float*)d_in[14];
    const float* fc1w  = (const float*)d_in[15];
    const float* fc1b  = (const float*)d_in[16];
    const float* fc2w  = (const float*)d_in[17];
    const float* fc2b  = (const float*)d_in[18];

    const int N = in_sizes[0] / 16;   // 20000
    const int E = in_sizes[2];        // 100000
    const int* src = eidx;
    const int* tgt = eidx + E;

    const int cap1 = ((E + 26 * (CH1 - 1)) + CH1 - 1) / CH1 * CH1;
    const int cap2 = ((E + 26 * (CH2 - 1)) + CH2 - 1) / CH2 * CH2;

    float* ws = (float*)d_ws;
    size_t off = 0;
    int*      hist = (int*)(ws + off);      off += 64;
    int*      cur  = (int*)(ws + off);      off += 64;
    int*      segp = (int*)(ws + off);      off += E;
    int*      ord1 = (int*)(ws + off);      off += cap1;   // ord1/ord2 contiguous
    int*      ord2 = (int*)(ws + off);      off += cap2;
    float*    U1   = ws + off;              off += 26 * 512;
    float*    V1   = ws + off;              off += 26 * 512;
    float*    U2   = ws + off;              off += 26 * 2048;
    float*    V2   = ws + off;              off += 26 * 2048;
    float*    AGG1 = ws + off;              off += (size_t)N * 32;   // AGG1/AGG2 contiguous
    float*    AGG2 = ws + off;              off += (size_t)N * 64;
    float*    H1b  = ws + off;              off += (size_t)N * 32;
    float*    H2b  = ws + off;              off += (size_t)N * 64;
    float*    H3b  = ws + off;              off += (size_t)N * 128;

    // 1. init: agg=-FLT_MAX, order arrays=-1, hist=0
    fill_kernel<<<512, 256, 0, stream>>>(AGG1, N * 96, ord1, cap1 + cap2, hist, 64);
    // 2. per-edge segment ranks + histograms
    assign_hist_kernel<<<(E + 255) / 256, 256, 0, stream>>>(ea, w1a, b1a, w2a, b2a, E, segp, hist);
    // 3. chunk-aligned bucket offsets (parallel load, LDS scan)
    scanpad_kernel<<<1, 64, 0, stream>>>(hist, cur);
    // 4. scatter edges into segment-sorted order arrays
    scatter_kernel<<<(E + 255) / 256, 256, 0, stream>>>(segp, E, cur, ord1, ord2);
    // 5. per-segment U/V tables, both convs (masks computed in-block, rank-based)
    build_uv_fused<<<dim3(10, 26), 256, 0, stream>>>(w1a, b1a, w1b, b1b, w2a, b2a, w2b, b2b,
                                                     U1, V1, U2, V2);
    // 6. conv1
    edge1_kernel<<<(cap1 / CH1 + 3) / 4, 256, 0, stream>>>(x, src, tgt, ea, ord1, U1, V1, AGG1);
    node_kernel<16, 32><<<(N * 32 + 255) / 256, 256, 0, stream>>>(x, AGG1, wr1, bias1, H1b, N);
    // 7. conv2
    edge2_kernel<<<(cap2 / CH2 + 3) / 4, 256, 0, stream>>>(H1b, src, tgt, ea, ord2, U2, V2, AGG2);
    node_kernel<32, 64><<<(N * 64 + 255) / 256, 256, 0, stream>>>(H1b, AGG2, wr2, bias2, H2b, N);
    // 8. trailing FCs + log_softmax
    fc1_kernel<<<(N * 128 + 255) / 256, 256, 0, stream>>>(H2b, fc1w, fc1b, H3b, N);
    fc2_kernel<<<(N + 3) / 4, 256, 0, stream>>>(H3b, fc2w, fc2b, (float*)d_out, N);
}

// Round 4
// 231.106 us; speedup vs baseline: 1.4739x; 1.2793x over previous
//
#include <hip/hip_runtime.h>
#include <float.h>
#include <math.h>

// NNConv net: 2x edge-conditioned conv (scalar edge attr) + 2 FC + log_softmax.
// W_e = a_e*U_s + V_s over <=26 breakpoint segments of the scalar edge attr.
// Edges bucketed by segment (chunk-aligned so a wave chunk is single-segment);
// per wave: U/V columns register-cached (lane = out channel), per-lane metadata
// gather + readlane broadcast, unrolled break-free chunk loop.
// R3: killed scratch demotion of Ur/Vr (VGPR_Count was 40 < 64 floats -> proof
// of spill) + data-dependent break that blocked pipelining; fused node2+fc1+fc2.

#define NCONST 25
#define CH1 32   // edges per wave chunk, conv1
#define CH2 16   // edges per wave chunk, conv2
#define PACK_MASK 0x1FFFF  // edge id < 2^17 (E = 100000)

__device__ __forceinline__ void atomicMaxFloat(float* addr, float val) {
    if (val >= 0.f) atomicMax((int*)addr, __float_as_int(val));
    else            atomicMin((unsigned int*)addr, __float_as_uint(val));
}
__device__ __forceinline__ float readlane_f(float v, int l) {
    return __int_as_float(__builtin_amdgcn_readlane(__float_as_int(v), l));
}

// Fill: agg regions with -FLT_MAX, order arrays with -1, hist with 0.
__global__ void fill_kernel(float* agg, int nAgg, int* ords, int nOrd, int* hist, int nH) {
    int i = blockIdx.x * blockDim.x + threadIdx.x;
    int stride = gridDim.x * blockDim.x;
    int total = nAgg + nOrd + nH;
    for (; i < total; i += stride) {
        if (i < nAgg) agg[i] = -FLT_MAX;
        else if (i < nAgg + nOrd) ords[i - nAgg] = -1;
        else hist[i - nAgg - nOrd] = 0;
    }
}

// Per edge: segment rank for both convs (j = #breakpoints < a), LDS-aggregated
// histograms, store packed (j1 | j2<<8).
__global__ void assign_hist_kernel(const float* __restrict__ ea,
                                   const float* __restrict__ w1a, const float* __restrict__ b1a,
                                   const float* __restrict__ w2a, const float* __restrict__ b2a,
                                   int E, int* __restrict__ segpack, int* __restrict__ hist) {
    __shared__ float t1[NCONST], t2[NCONST];
    __shared__ int lh[64];
    int tid = threadIdx.x;
    if (tid < NCONST) {
        float w = w1a[tid]; t1[tid] = (w != 0.f) ? (-b1a[tid] / w) : INFINITY;
        float v = w2a[tid]; t2[tid] = (v != 0.f) ? (-b2a[tid] / v) : INFINITY;
    }
    if (tid < 64) lh[tid] = 0;
    __syncthreads();
    int e = blockIdx.x * blockDim.x + tid;
    bool valid = e < E;
    if (valid) {
        float a = ea[e];
        int j1 = 0, j2 = 0;
        for (int k = 0; k < NCONST; ++k) { j1 += (t1[k] < a); j2 += (t2[k] < a); }
        segpack[e] = j1 | (j2 << 8);
        atomicAdd(&lh[j1], 1); atomicAdd(&lh[32 + j2], 1);
    }
    __syncthreads();
    if (tid < 64 && lh[tid]) atomicAdd(&hist[tid], lh[tid]);
}

// Parallel hist load through LDS, then two lanes do the 26-step chunk-aligned
// exclusive scan LDS-resident.
__global__ void scanpad_kernel(const int* __restrict__ hist, int* __restrict__ cur) {
    __shared__ int h[64];
    int tid = threadIdx.x;
    h[tid] = hist[tid];
    __syncthreads();
    if (tid == 0) {
        int off = 0;
        for (int j = 0; j < 26; ++j) { cur[j] = off; off += ((h[j] + CH1 - 1) / CH1) * CH1; }
    } else if (tid == 1) {
        int off = 0;
        for (int j = 0; j < 26; ++j) { cur[32 + j] = off; off += ((h[32 + j] + CH2 - 1) / CH2) * CH2; }
    }
}

// Block-aggregated scatter: LDS rank + one global atomicAdd per (block,bin).
__global__ void scatter_kernel(const int* __restrict__ segpack, int E, int* __restrict__ cur,
                               int* __restrict__ order1, int* __restrict__ order2) {
    __shared__ int lh[64], lb[64];
    int tid = threadIdx.x;
    if (tid < 64) lh[tid] = 0;
    __syncthreads();
    int e = blockIdx.x * blockDim.x + tid;
    bool valid = e < E;
    int j1 = 0, j2 = 0, r1 = 0, r2 = 0;
    if (valid) {
        int p = segpack[e]; j1 = p & 0xFF; j2 = p >> 8;
        r1 = atomicAdd(&lh[j1], 1); r2 = atomicAdd(&lh[32 + j2], 1);
    }
    __syncthreads();
    if (tid < 64 && lh[tid]) lb[tid] = atomicAdd(&cur[tid], lh[tid]);
    __syncthreads();
    if (valid) {
        order1[lb[j1] + r1] = (j1 << 17) | e;
        order2[lb[32 + j2] + r2] = (j2 << 17) | e;
    }
}

// U_s = sum_{k active} wa_k*wb_k ; V_s = sum_{k active} ba_k*wb_k + bb.
// Rank-based mask per block (LDS-resident, no sort): unit k active in segment j
// iff wa>0: j>r_k; wa<0: j<=r_k; wa==0: ba>0, with r_k = #{l: t_l < t_k}.
__global__ void build_uv_fused(const float* w1a, const float* b1a, const float* w1b, const float* b1b,
                               const float* w2a, const float* b2a, const float* w2b, const float* b2b,
                               float* U1, float* V1, float* U2, float* V2) {
    __shared__ float swa[NCONST], sba[NCONST], st[NCONST];
    __shared__ int sr[NCONST];
    __shared__ unsigned msk_sh;
    int seg = blockIdx.y;
    int bx = blockIdx.x;
    int conv = (bx < 2) ? 0 : 1;
    const float* wa = conv ? w2a : w1a;
    const float* ba = conv ? b2a : b1a;
    int tid = threadIdx.x;
    if (tid < NCONST) {
        float w = wa[tid], b = ba[tid];
        swa[tid] = w; sba[tid] = b;
        st[tid] = (w != 0.f) ? (-b / w) : INFINITY;
    }
    __syncthreads();
    if (tid < NCONST) {
        int rk = 0;
        for (int l = 0; l < NCONST; ++l) rk += (st[l] < st[tid]) ? 1 : 0;
        sr[tid] = rk;
    }
    __syncthreads();
    if (tid == 0) {
        unsigned m = 0;
        for (int k = 0; k < NCONST; ++k) {
            float w = swa[k];
            bool act = (w > 0.f) ? (seg > sr[k])
                     : (w < 0.f) ? (seg <= sr[k])
                                 : (sba[k] > 0.f);
            if (act) m |= (1u << k);
        }
        msk_sh = m;
    }
    __syncthreads();
    unsigned msk = msk_sh;
    if (conv == 0) {
        int idx = bx * 256 + tid;           // < 512
        float u = 0.f, v = 0.f;
        for (int k = 0; k < NCONST; ++k)
            if (msk & (1u << k)) { float w = w1b[k * 512 + idx]; u = fmaf(swa[k], w, u); v = fmaf(sba[k], w, v); }
        v += b1b[idx];
        U1[seg * 512 + idx] = u; V1[seg * 512 + idx] = v;
    } else {
        int idx = (bx - 2) * 256 + tid;     // < 2048
        float u = 0.f, v = 0.f;
        for (int k = 0; k < NCONST; ++k)
            if (msk & (1u << k)) { float w = w2b[k * 2048 + idx]; u = fmaf(swa[k], w, u); v = fmaf(sba[k], w, v); }
        v += b2b[idx];
        U2[seg * 2048 + idx] = u; V2[seg * 2048 + idx] = v;
    }
}

// conv1 edges: IC=16, OC=32, half-wave per edge (2 edges/iter). U/V loaded once
// (chunk is single-segment). Metadata pre-gathered per lane, readlane broadcast.
__global__ void edge1_kernel(const float* __restrict__ xin, const int* __restrict__ src,
                             const int* __restrict__ tgt, const float* __restrict__ ea,
                             const int* __restrict__ order, int cap,
                             const float* __restrict__ U, const float* __restrict__ V,
                             float* __restrict__ agg) {
    int wid = (blockIdx.x * blockDim.x + threadIdx.x) >> 6;
    int lane = threadIdx.x & 63;
    int base = wid * CH1;
    if (base >= cap) return;
    int pk = order[base + (lane & (CH1 - 1))];
    int p0 = __builtin_amdgcn_readfirstlane(pk);
    if (p0 < 0) return;                        // whole-pad chunk past used region
    int seg = p0 >> 17;
    int ev = (pk < 0) ? 0 : (pk & PACK_MASK);
    int sv = src[ev], tv = tgt[ev];
    float av = ea[ev];
    int half = lane >> 5, c = lane & 31;
    float Ur[16], Vr[16];
    {
        const float* Us = U + seg * 512 + c;
        const float* Vs = V + seg * 512 + c;
#pragma unroll
        for (int i = 0; i < 16; ++i) { Ur[i] = Us[i * 32]; Vr[i] = Vs[i * 32]; }
    }
#pragma unroll
    for (int t = 0; t < CH1; t += 2) {
        int pA = __builtin_amdgcn_readlane(pk, t);
        int pB = __builtin_amdgcn_readlane(pk, t + 1);
        int sA = __builtin_amdgcn_readlane(sv, t);
        int sB = __builtin_amdgcn_readlane(sv, t + 1);
        int tA = __builtin_amdgcn_readlane(tv, t);
        int tB = __builtin_amdgcn_readlane(tv, t + 1);
        float aA = readlane_f(av, t);
        float aB = readlane_f(av, t + 1);
        const float* xA = xin + sA * 16;
        const float* xB = xin + sB * 16;
        float ah = half ? aB : aA;
        int   th = half ? tB : tA;
        int   ph = half ? pB : pA;
        float acc = 0.f;
#pragma unroll
        for (int i = 0; i < 16; ++i) {
            float xi = half ? xB[i] : xA[i];
            acc = fmaf(xi, fmaf(ah, Ur[i], Vr[i]), acc);
        }
        if (ph >= 0) atomicMaxFloat(&agg[th * 32 + c], acc);
    }
}

// conv2 edges: IC=32, OC=64, lane = out channel, A/B edge pair per iteration.
__global__ void edge2_kernel(const float* __restrict__ xin, const int* __restrict__ src,
                             const int* __restrict__ tgt, const float* __restrict__ ea,
                             const int* __restrict__ order, int cap,
                             const float* __restrict__ U, const float* __restrict__ V,
                             float* __restrict__ agg) {
    int wid = (blockIdx.x * blockDim.x + threadIdx.x) >> 6;
    int lane = threadIdx.x & 63;
    int base = wid * CH2;
    if (base >= cap) return;
    int pk = order[base + (lane & (CH2 - 1))];
    int p0 = __builtin_amdgcn_readfirstlane(pk);
    if (p0 < 0) return;
    int seg = p0 >> 17;
    int ev = (pk < 0) ? 0 : (pk & PACK_MASK);
    int sv = src[ev], tv = tgt[ev];
    float av = ea[ev];
    float Ur[32], Vr[32];
    {
        const float* Us = U + seg * 2048 + lane;
        const float* Vs = V + seg * 2048 + lane;
#pragma unroll
        for (int i = 0; i < 32; ++i) { Ur[i] = Us[i * 64]; Vr[i] = Vs[i * 64]; }
    }
#pragma unroll
    for (int t = 0; t < CH2; t += 2) {
        int pA = __builtin_amdgcn_readlane(pk, t);
        int pB = __builtin_amdgcn_readlane(pk, t + 1);
        int sA = __builtin_amdgcn_readlane(sv, t);
        int sB = __builtin_amdgcn_readlane(sv, t + 1);
        int tA = __builtin_amdgcn_readlane(tv, t);
        int tB = __builtin_amdgcn_readlane(tv, t + 1);
        float aA = readlane_f(av, t);
        float aB = readlane_f(av, t + 1);
        const float* xA = xin + sA * 32;
        const float* xB = xin + sB * 32;
        float accA = 0.f, accB = 0.f;
#pragma unroll
        for (int i = 0; i < 32; ++i) {
            accA = fmaf(xA[i], fmaf(aA, Ur[i], Vr[i]), accA);
            accB = fmaf(xB[i], fmaf(aB, Ur[i], Vr[i]), accB);
        }
        if (pA >= 0) atomicMaxFloat(&agg[tA * 64 + lane], accA);
        if (pB >= 0) atomicMaxFloat(&agg[tB * 64 + lane], accB);
    }
}

// conv1 node update: out = elu( fixup(agg) + x @ wr1 + bias1 )
__global__ void node1_kernel(const float* __restrict__ xin, const float* __restrict__ agg,
                             const float* __restrict__ wroot, const float* __restrict__ bias,
                             float* __restrict__ out, int N) {
    int idx = blockIdx.x * blockDim.x + threadIdx.x;
    if (idx >= N * 32) return;
    int n = idx >> 5, c = idx & 31;
    float v = agg[idx];
    if (v == -FLT_MAX) v = 0.f;
    float acc = v + bias[c];
#pragma unroll
    for (int i = 0; i < 16; ++i) acc = fmaf(xin[n * 16 + i], wroot[i * 32 + c], acc);
    out[idx] = acc > 0.f ? acc : expm1f(acc);
}

// Fused tail: node2 (agg fixup + root matmul + elu) -> fc1+elu -> fc2+log_softmax.
// One wave per node (4 nodes/block), h2/h3 rows staged in LDS, float4 broadcasts.
__global__ void tail_kernel(const float* __restrict__ h1, const float* __restrict__ agg2,
                            const float* __restrict__ wr2, const float* __restrict__ bias2,
                            const float* __restrict__ fc1w, const float* __restrict__ fc1b,
                            const float* __restrict__ fc2w, const float* __restrict__ fc2b,
                            float* __restrict__ out) {
    __shared__ __align__(16) float h2sh[4][64];
    __shared__ __align__(16) float h3sh[4][128];
    int w = threadIdx.x >> 6, lane = threadIdx.x & 63;
    int n = blockIdx.x * 4 + w;
    // node2
    float v = agg2[n * 64 + lane];
    if (v == -FLT_MAX) v = 0.f;
    float acc = v + bias2[lane];
    const float* xr = h1 + n * 32;             // wave-uniform row
#pragma unroll
    for (int i = 0; i < 32; ++i) acc = fmaf(xr[i], wr2[i * 64 + lane], acc);
    h2sh[w][lane] = acc > 0.f ? acc : expm1f(acc);
    __syncthreads();
    // fc1: two outputs per lane
    const float4* h2v = (const float4*)h2sh[w];
#pragma unroll
    for (int r = 0; r < 2; ++r) {
        int o = lane + r * 64;
        float a1 = fc1b[o];
#pragma unroll
        for (int q = 0; q < 16; ++q) {
            float4 hv = h2v[q];
            a1 = fmaf(hv.x, fc1w[(q * 4 + 0) * 128 + o], a1);
            a1 = fmaf(hv.y, fc1w[(q * 4 + 1) * 128 + o], a1);
            a1 = fmaf(hv.z, fc1w[(q * 4 + 2) * 128 + o], a1);
            a1 = fmaf(hv.w, fc1w[(q * 4 + 3) * 128 + o], a1);
        }
        h3sh[w][o] = a1 > 0.f ? a1 : expm1f(a1);
    }
    __syncthreads();
    // fc2 + log_softmax
    float logit = -FLT_MAX;
    const float4* h3v = (const float4*)h3sh[w];
    if (lane < 10) {
        float a2 = fc2b[lane];
#pragma unroll
        for (int q = 0; q < 32; ++q) {
            float4 hv = h3v[q];
            a2 = fmaf(hv.x, fc2w[(q * 4 + 0) * 10 + lane], a2);
            a2 = fmaf(hv.y, fc2w[(q * 4 + 1) * 10 + lane], a2);
            a2 = fmaf(hv.z, fc2w[(q * 4 + 2) * 10 + lane], a2);
            a2 = fmaf(hv.w, fc2w[(q * 4 + 3) * 10 + lane], a2);
        }
        logit = a2;
    }
    float mx = -FLT_MAX;
#pragma unroll
    for (int i = 0; i < 10; ++i) mx = fmaxf(mx, __shfl(logit, i, 64));
    float s = 0.f;
#pragma unroll
    for (int i = 0; i < 10; ++i) s += expf(__shfl(logit, i, 64) - mx);
    if (lane < 10) out[n * 10 + lane] = logit - mx - logf(s);
}

extern "C" void kernel_launch(void* const* d_in, const int* in_sizes, int n_in,
                              void* d_out, int out_size, void* d_ws, size_t ws_size,
                              hipStream_t stream) {
    const float* x     = (const float*)d_in[0];
    const int*   eidx  = (const int*)d_in[1];
    const float* ea    = (const float*)d_in[2];
    const float* w1a   = (const float*)d_in[3];
    const float* b1a   = (const float*)d_in[4];
    const float* w1b   = (const float*)d_in[5];
    const float* b1b   = (const float*)d_in[6];
    const float* wr1   = (const float*)d_in[7];
    const float* bias1 = (const float*)d_in[8];
    const float* w2a   = (const float*)d_in[9];
    const float* b2a   = (const float*)d_in[10];
    const float* w2b   = (const float*)d_in[11];
    const float* b2b   = (const float*)d_in[12];
    const float* wr2   = (const float*)d_in[13];
    const float* bias2 = (const float*)d_in[14];
    const float* fc1w  = (const float*)d_in[15];
    const float* fc1b  = (const float*)d_in[16];
    const float* fc2w  = (const float*)d_in[17];
    const float* fc2b  = (const float*)d_in[18];

    const int N = in_sizes[0] / 16;   // 20000
    const int E = in_sizes[2];        // 100000
    const int* src = eidx;
    const int* tgt = eidx + E;

    const int cap1 = ((E + 26 * (CH1 - 1)) + CH1 - 1) / CH1 * CH1;
    const int cap2 = ((E + 26 * (CH2 - 1)) + CH2 - 1) / CH2 * CH2;

    float* ws = (float*)d_ws;
    size_t off = 0;
    int*      hist = (int*)(ws + off);      off += 64;
    int*      cur  = (int*)(ws + off);      off += 64;
    int*      segp = (int*)(ws + off);      off += E;
    int*      ord1 = (int*)(ws + off);      off += cap1;   // ord1/ord2 contiguous
    int*      ord2 = (int*)(ws + off);      off += cap2;
    float*    U1   = ws + off;              off += 26 * 512;
    float*    V1   = ws + off;              off += 26 * 512;
    float*    U2   = ws + off;              off += 26 * 2048;
    float*    V2   = ws + off;              off += 26 * 2048;
    float*    AGG1 = ws + off;              off += (size_t)N * 32;   // AGG1/AGG2 contiguous
    float*    AGG2 = ws + off;              off += (size_t)N * 64;
    float*    H1b  = ws + off;              off += (size_t)N * 32;

    // 1. init: agg=-FLT_MAX, order arrays=-1, hist=0
    fill_kernel<<<512, 256, 0, stream>>>(AGG1, N * 96, ord1, cap1 + cap2, hist, 64);
    // 2. per-edge segment ranks + histograms
    assign_hist_kernel<<<(E + 255) / 256, 256, 0, stream>>>(ea, w1a, b1a, w2a, b2a, E, segp, hist);
    // 3. chunk-aligned bucket offsets
    scanpad_kernel<<<1, 64, 0, stream>>>(hist, cur);
    // 4. scatter edges into segment-sorted order arrays
    scatter_kernel<<<(E + 255) / 256, 256, 0, stream>>>(segp, E, cur, ord1, ord2);
    // 5. per-segment U/V tables, both convs
    build_uv_fused<<<dim3(10, 26), 256, 0, stream>>>(w1a, b1a, w1b, b1b, w2a, b2a, w2b, b2b,
                                                     U1, V1, U2, V2);
    // 6. conv1
    {
        int waves = cap1 / CH1;
        edge1_kernel<<<(waves + 3) / 4, 256, 0, stream>>>(x, src, tgt, ea, ord1, cap1, U1, V1, AGG1);
    }
    node1_kernel<<<(N * 32 + 255) / 256, 256, 0, stream>>>(x, AGG1, wr1, bias1, H1b, N);
    // 7. conv2
    {
        int waves = cap2 / CH2;
        edge2_kernel<<<(waves + 3) / 4, 256, 0, stream>>>(H1b, src, tgt, ea, ord2, cap2, U2, V2, AGG2);
    }
    // 8. fused node2 + fc1 + fc2 + log_softmax (N % 4 == 0)
    tail_kernel<<<N / 4, 256, 0, stream>>>(H1b, AGG2, wr2, bias2, fc1w, fc1b, fc2w, fc2b, (float*)d_out);
}